// Round 1
// baseline (1893.807 us; speedup 1.0000x reference)
//
#include <hip/hip_runtime.h>
#include <stdint.h>

#define B_  2
#define T_  2048
#define D_  1024
#define H_  4
#define S_  64
#define W_  512
#define CK_ 256
#define NC_ 32      // T_/64 chunks
#define BT_ 4096

__device__ __forceinline__ float bf2f(unsigned short u){ return __uint_as_float(((unsigned int)u)<<16); }
__device__ __forceinline__ unsigned short f2bf(float f){
  unsigned int u = __float_as_uint(f);
  u += 0x7fffu + ((u>>16)&1u);
  return (unsigned short)(u>>16);
}
__device__ __forceinline__ float bflo(unsigned int p){ return __uint_as_float(p<<16); }
__device__ __forceinline__ float bfhi(unsigned int p){ return __uint_as_float(p & 0xffff0000u); }

// ---------------- RMSNorm: x(B*T,D) -> out(B*T,D) fp32 ----------------
__global__ void rmsnorm_kernel(const float* __restrict__ x, const float* __restrict__ w,
                               float* __restrict__ out){
  int row = blockIdx.x, tid = threadIdx.x;
  const float* xr = x + (size_t)row*D_;
  float v0=xr[tid], v1=xr[tid+256], v2=xr[tid+512], v3=xr[tid+768];
  __shared__ float red[256];
  red[tid] = v0*v0+v1*v1+v2*v2+v3*v3;
  __syncthreads();
  for(int s=128;s>0;s>>=1){ if(tid<s) red[tid]+=red[tid+s]; __syncthreads(); }
  float r = rsqrtf(red[0]/(float)D_ + 1e-5f);
  float* orow = out + (size_t)row*D_;
  orow[tid]     = v0*r*w[tid];
  orow[tid+256] = v1*r*w[tid+256];
  orow[tid+512] = v2*r*w[tid+512];
  orow[tid+768] = v3*r*w[tid+768];
}

// ---------------- GEMM-NT: C[M,N] = A[M,K] * Wt[N,K]^T ----------------
// optional fp32 output Cf, optional bf16 output Cbf
__global__ __launch_bounds__(256) void gemm_nt(const float* __restrict__ A, const float* __restrict__ Wt,
                     float* __restrict__ Cf, unsigned short* __restrict__ Cbf,
                     int M, int N, int K){
  __shared__ float As[16][68];
  __shared__ float Bs[16][68];
  int tid = threadIdx.x;
  int tx = tid & 15, ty = tid >> 4;
  int row0 = blockIdx.y*64, col0 = blockIdx.x*64;
  int kq = tid & 15;
  int mq = tid >> 4;
  float acc[4][4] = {};
  for(int kt=0; kt<K; kt+=16){
    #pragma unroll
    for(int r=0;r<4;r++){
      As[kq][mq + r*16] = A [(size_t)(row0 + mq + r*16)*K + kt + kq];
      Bs[kq][mq + r*16] = Wt[(size_t)(col0 + mq + r*16)*K + kt + kq];
    }
    __syncthreads();
    #pragma unroll
    for(int kk=0;kk<16;kk++){
      float a0=As[kk][ty*4+0],a1=As[kk][ty*4+1],a2=As[kk][ty*4+2],a3=As[kk][ty*4+3];
      float b0=Bs[kk][tx*4+0],b1=Bs[kk][tx*4+1],b2=Bs[kk][tx*4+2],b3=Bs[kk][tx*4+3];
      acc[0][0]+=a0*b0; acc[0][1]+=a0*b1; acc[0][2]+=a0*b2; acc[0][3]+=a0*b3;
      acc[1][0]+=a1*b0; acc[1][1]+=a1*b1; acc[1][2]+=a1*b2; acc[1][3]+=a1*b3;
      acc[2][0]+=a2*b0; acc[2][1]+=a2*b1; acc[2][2]+=a2*b2; acc[2][3]+=a2*b3;
      acc[3][0]+=a3*b0; acc[3][1]+=a3*b1; acc[3][2]+=a3*b2; acc[3][3]+=a3*b3;
    }
    __syncthreads();
  }
  #pragma unroll
  for(int i=0;i<4;i++){
    #pragma unroll
    for(int j=0;j<4;j++){
      size_t idx = (size_t)(row0+ty*4+i)*N + col0+tx*4+j;
      float val = acc[i][j];
      if(Cf)  Cf[idx]  = val;
      if(Cbf) Cbf[idx] = f2bf(val);
    }
  }
}

// ---------------- softmax over 256 (in place), one row per block ----------------
__global__ void softmax256_kernel(float* __restrict__ g){
  int row = blockIdx.x, tid = threadIdx.x;
  float x = g[(size_t)row*256+tid];
  __shared__ float red[256];
  red[tid]=x; __syncthreads();
  for(int s=128;s>0;s>>=1){ if(tid<s) red[tid]=fmaxf(red[tid],red[tid+s]); __syncthreads(); }
  float m = red[0]; __syncthreads();
  float e = expf(x-m);
  red[tid]=e; __syncthreads();
  for(int s=128;s>0;s>>=1){ if(tid<s) red[tid]+=red[tid+s]; __syncthreads(); }
  g[(size_t)row*256+tid] = e/red[0];
}

// ---------------- per-chunk outer product states ----------------
// P1 (transpose_out=0): out[bhn][c][s] = sum_u in1[b,t0+u,h*256+c] * g[b,t0+u,h*64+s]
// P2 (transpose_out=1): out[bhn][s][c] = same sum, transposed store
__global__ __launch_bounds__(256) void chunk_outer_kernel(const float* __restrict__ in1f,
    const unsigned short* __restrict__ in1bf,
    const float* __restrict__ g, float* __restrict__ out, int transpose_out){
  int n=blockIdx.x, h=blockIdx.y, b=blockIdx.z;
  int tid=threadIdx.x, t0=n*64;
  __shared__ float g_lds[64][68];
  for(int i=0;i<64;i+=4){
    int rr = i + (tid>>6), cc = tid&63;
    g_lds[rr][cc] = g[((size_t)(b*T_ + t0 + rr))*256 + h*64 + cc];
  }
  __syncthreads();
  float acc[64]={};
  for(int u=0;u<64;u++){
    size_t idx = ((size_t)(b*T_ + t0 + u))*D_ + h*CK_ + tid;
    float a = in1f ? in1f[idx] : bf2f(in1bf[idx]);
    #pragma unroll
    for(int s=0;s<64;s++) acc[s] += a*g_lds[u][s];
  }
  size_t base = (size_t)(b*H_+h)*NC_ + n;
  if(transpose_out){
    #pragma unroll 4
    for(int s=0;s<64;s++) out[(base*64+s)*256 + tid] = acc[s];
  } else {
    #pragma unroll 4
    for(int s=0;s<64;s++) out[(base*256+tid)*64 + s] = acc[s];
  }
}

// ---------------- exclusive prefix over chunks (in place) ----------------
// arr layout [B*H][NC][16384]
__global__ void chunk_prefix_kernel(float* __restrict__ arr){
  int idx = blockIdx.x*256 + threadIdx.x;
  int bh = idx >> 14, e = idx & 16383;
  float run = 0.f;
  size_t base = (size_t)bh*NC_*16384 + e;
  for(int n=0;n<NC_;n++){
    size_t a = base + (size_t)n*16384;
    float t = arr[a]; arr[a] = run; run += t;
  }
}

// ---------------- sc_state[t,s] = q[t]·S1[:,s] + tril(q·s^T)·g ----------------
__global__ __launch_bounds__(256) void sc_state_kernel(const unsigned short* __restrict__ q_bf,
    const unsigned short* __restrict__ s_bf,
    const float* __restrict__ g, const float* __restrict__ S1, float* __restrict__ sc_state){
  int n=blockIdx.x, h=blockIdx.y, b=blockIdx.z;
  int tid=threadIdx.x, t0=n*64;
  __shared__ unsigned short s_lds[64*260];
  __shared__ float A_lds[64*65];
  for(int i=0;i<64;i++)
    s_lds[i*260+tid] = s_bf[((size_t)(b*T_+t0+i))*D_ + h*CK_ + tid];
  __syncthreads();
  int u = tid & 63;
  #pragma unroll 1
  for(int kk=0;kk<16;kk++){
    int t = (tid>>6) + kk*4;
    const unsigned short* qr = q_bf + ((size_t)(b*T_+t0+t))*D_ + h*CK_;
    float dot=0.f;
    for(int c=0;c<256;c+=2){
      unsigned int qp = *(const unsigned int*)(qr + c);
      unsigned int sp = *(const unsigned int*)(&s_lds[u*260+c]);
      dot += bflo(qp)*bflo(sp) + bfhi(qp)*bfhi(sp);
    }
    A_lds[t*65+u] = (u<=t)? dot : 0.f;
  }
  __syncthreads();
  int s = tid & 63, tb = tid >> 6;
  float acc[16]={};
  size_t s1base = ((size_t)(b*H_+h)*NC_+n)*16384;
  for(int c=0;c<256;c++){
    float st1 = S1[s1base + c*64 + s];
    #pragma unroll
    for(int i=0;i<16;i++){
      float qv = bf2f(q_bf[((size_t)(b*T_+t0+tb*16+i))*D_ + h*CK_ + c]);
      acc[i] += qv*st1;
    }
  }
  for(int uu=0;uu<64;uu++){
    float gv = g[((size_t)(b*T_+t0+uu))*256 + h*64 + s];
    #pragma unroll
    for(int i=0;i<16;i++){
      int t = tb*16+i;
      if(uu<=t) acc[i] += A_lds[t*65+uu]*gv;
    }
  }
  #pragma unroll
  for(int i=0;i<16;i++)
    sc_state[((size_t)(b*H_+h)*T_ + t0+tb*16+i)*64 + s] = acc[i];
}

// ---------------- fused window attention + joint softmax ----------------
// outputs: o (pre-normalized window output, [b][h][t][c]) and p_state [b][h][t][s]
__global__ __launch_bounds__(256) void window_attn_kernel(const unsigned short* __restrict__ q_bf,
    const unsigned short* __restrict__ k_bf,
    const float* __restrict__ v, const float* __restrict__ sc_state,
    float* __restrict__ o, float* __restrict__ p_state){
  int nt=blockIdx.x, h=blockIdx.y, b=blockIdx.z;
  int tid=threadIdx.x, t0=nt*64;
  __shared__ unsigned short k_lds[64*260];
  __shared__ float S_lds[64*68];
  __shared__ float m_lds[64], l_lds[64], al_lds[64];
  float slope = exp2f(-2.0f*(float)h);   // 2^(-8h/H), H=4
  size_t scbase = ((size_t)(b*H_+h)*T_ + t0)*64;
  if(tid<64){
    const float* sr = sc_state + scbase + (size_t)tid*64;
    float m=-1e30f;
    for(int s=0;s<64;s++) m = fmaxf(m, sr[s]);
    float l=0.f;
    for(int s=0;s<64;s++) l += expf(sr[s]-m);
    m_lds[tid]=m; l_lds[tid]=l;
  }
  float o_acc[64];
  #pragma unroll
  for(int t=0;t<64;t++) o_acc[t]=0.f;
  __syncthreads();
  int jt0 = (nt>=8)? nt-8 : 0;
  for(int jt=jt0; jt<=nt; jt++){
    int j0 = jt*64;
    for(int i=0;i<64;i++)
      k_lds[i*260+tid] = k_bf[((size_t)(b*T_+j0+i))*D_ + h*CK_ + tid];
    __syncthreads();
    int u = tid & 63;
    #pragma unroll 1
    for(int kk=0;kk<16;kk++){
      int t = (tid>>6) + kk*4;
      const unsigned short* qr = q_bf + ((size_t)(b*T_+t0+t))*D_ + h*CK_;
      float dot=0.f;
      for(int c=0;c<256;c+=2){
        unsigned int qp = *(const unsigned int*)(qr+c);
        unsigned int kp = *(const unsigned int*)(&k_lds[u*260+c]);
        dot += bflo(qp)*bflo(kp) + bfhi(qp)*bfhi(kp);
      }
      int d = (t0+t) - (j0+u);
      S_lds[t*68+u] = (d>=0 && d<W_) ? dot - slope*(float)d : -1e30f;
    }
    __syncthreads();
    if(tid<64){
      int t=tid;
      float m_old=m_lds[t], mx=m_old;
      for(int uu=0;uu<64;uu++) mx = fmaxf(mx, S_lds[t*68+uu]);
      float al = expf(m_old-mx);
      float sum = l_lds[t]*al;
      for(int uu=0;uu<64;uu++){ float p = expf(S_lds[t*68+uu]-mx); S_lds[t*68+uu]=p; sum+=p; }
      m_lds[t]=mx; l_lds[t]=sum; al_lds[t]=al;
    }
    __syncthreads();
    #pragma unroll
    for(int t=0;t<64;t++) o_acc[t] *= al_lds[t];
    for(int uu=0;uu<64;uu++){
      float vv = v[((size_t)(b*T_+j0+uu))*D_ + h*CK_ + tid];
      #pragma unroll
      for(int t=0;t<64;t++) o_acc[t] += S_lds[t*68+uu]*vv;
    }
    __syncthreads();
  }
  #pragma unroll 4
  for(int t=0;t<64;t++)
    o[((size_t)(b*H_+h)*T_ + t0+t)*256 + tid] = o_acc[t] / l_lds[t];
  if(tid<64){
    const float* sr = sc_state + scbase + (size_t)tid*64;
    float m=m_lds[tid], l=l_lds[tid];
    float* pr = p_state + scbase + (size_t)tid*64;
    for(int s=0;s<64;s++) pr[s] = expf(sr[s]-m)/l;
  }
}

// ---------------- o += p_state @ SG + tril(p_state·g^T) @ v ----------------
__global__ __launch_bounds__(256) void o_state_kernel(const float* __restrict__ p_state,
    const float* __restrict__ g,
    const float* __restrict__ v, const float* __restrict__ SG, float* __restrict__ o){
  int n=blockIdx.x, h=blockIdx.y, b=blockIdx.z;
  int tid=threadIdx.x, t0=n*64;
  __shared__ float p_lds[64*69];
  __shared__ float g_lds[64*69];
  __shared__ float M_lds[64*65];
  for(int i=0;i<16;i++){
    int rr = (tid>>6) + i*4, cc = tid&63;
    p_lds[rr*69+cc] = p_state[((size_t)(b*H_+h)*T_ + t0+rr)*64 + cc];
    g_lds[rr*69+cc] = g[((size_t)(b*T_+t0+rr))*256 + h*64 + cc];
  }
  __syncthreads();
  int u = tid & 63;
  #pragma unroll 1
  for(int kk=0;kk<16;kk++){
    int t = (tid>>6) + kk*4;
    float dot=0.f;
    #pragma unroll
    for(int s=0;s<64;s++) dot += p_lds[t*69+s]*g_lds[u*69+s];
    M_lds[t*65+u] = (u<=t)? dot : 0.f;
  }
  __syncthreads();
  float acc[64];
  #pragma unroll
  for(int t=0;t<64;t++) acc[t]=0.f;
  size_t sgbase = ((size_t)(b*H_+h)*NC_+n)*16384;
  for(int s=0;s<64;s++){
    float gsc = SG[sgbase + s*256 + tid];
    #pragma unroll
    for(int t=0;t<64;t++) acc[t] += p_lds[t*69+s]*gsc;
  }
  for(int uu=0;uu<64;uu++){
    float vv = v[((size_t)(b*T_+t0+uu))*D_ + h*CK_ + tid];
    #pragma unroll
    for(int t=0;t<64;t++) acc[t] += M_lds[t*65+uu]*vv;
  }
  #pragma unroll 4
  for(int t=0;t<64;t++){
    size_t oi = ((size_t)(b*H_+h)*T_ + t0+t)*256 + tid;
    o[oi] += acc[t];
  }
}

// ---------------- swish + rmsnorm, gather heads -> (B*T, D) ----------------
__global__ void swish_rms_kernel(const float* __restrict__ o, const float* __restrict__ w,
                                 float* __restrict__ o2){
  int bt=blockIdx.x, tid=threadIdx.x;
  int b = bt >> 11, t = bt & 2047;
  float y[4]; float ss=0.f;
  #pragma unroll
  for(int hh=0;hh<4;hh++){
    float x = o[((size_t)(b*H_+hh)*T_ + t)*256 + tid];
    float yy = x / (1.f + expf(-x));
    y[hh]=yy; ss += yy*yy;
  }
  __shared__ float red[256];
  red[tid]=ss; __syncthreads();
  for(int s2=128;s2>0;s2>>=1){ if(tid<s2) red[tid]+=red[tid+s2]; __syncthreads(); }
  float r = rsqrtf(red[0]/1024.f + 1e-5f);
  #pragma unroll
  for(int hh=0;hh<4;hh++)
    o2[(size_t)bt*1024 + hh*256 + tid] = y[hh]*r*w[hh*256+tid];
}

extern "C" void kernel_launch(void* const* d_in, const int* in_sizes, int n_in,
                              void* d_out, int out_size, void* d_ws, size_t ws_size,
                              hipStream_t stream){
  const float* hidden = (const float*)d_in[0];
  const float* w_norm = (const float*)d_in[1];
  const float* Wq = (const float*)d_in[2];
  const float* Wk = (const float*)d_in[3];
  const float* Wv = (const float*)d_in[4];
  const float* Ws = (const float*)d_in[5];
  const float* Wg = (const float*)d_in[6];
  const float* Wo = (const float*)d_in[7];
  float* out = (float*)d_out;

  char* p = (char*)d_ws;
  auto alloc = [&](size_t bytes)->void*{ void* r = (void*)p; p += (bytes + 255) & ~(size_t)255; return r; };
  float* h   = (float*)alloc(16777216);           // (4096,1024) f32
  float* v   = (float*)alloc(16777216);           // (4096,1024) f32
  float* g   = (float*)alloc(4194304);            // (4096,256)  f32
  float* P1  = (float*)alloc(16777216);           // (8,32,256,64) f32 -> excl prefix
  float* P2  = (float*)alloc(16777216);           // (8,32,64,256) f32 -> excl prefix
  float* sc  = (float*)alloc(4194304);            // (8,2048,64)
  float* ps  = (float*)alloc(4194304);            // (8,2048,64)
  float* o   = (float*)alloc(16777216);           // (8,2048,256)
  unsigned short* q_bf = (unsigned short*)alloc(8388608);
  unsigned short* k_bf = (unsigned short*)alloc(8388608);
  unsigned short* s_bf = (unsigned short*)alloc(8388608);
  float* o2 = h; // h dead after projections; reuse for post-swish activations

  rmsnorm_kernel<<<4096,256,0,stream>>>(hidden, w_norm, h);
  dim3 g64(16,64), ggrid(4,64);
  gemm_nt<<<g64,256,0,stream>>>(h, Wq, nullptr, q_bf, 4096,1024,1024);
  gemm_nt<<<g64,256,0,stream>>>(h, Wk, nullptr, k_bf, 4096,1024,1024);
  gemm_nt<<<g64,256,0,stream>>>(h, Wv, v, nullptr, 4096,1024,1024);
  gemm_nt<<<g64,256,0,stream>>>(h, Ws, nullptr, s_bf, 4096,1024,1024);
  gemm_nt<<<ggrid,256,0,stream>>>(h, Wg, g, nullptr, 4096,256,1024);
  softmax256_kernel<<<4096,256,0,stream>>>(g);
  dim3 gc(32,4,2);
  chunk_outer_kernel<<<gc,256,0,stream>>>(nullptr, s_bf, g, P1, 0);
  chunk_outer_kernel<<<gc,256,0,stream>>>(v, nullptr, g, P2, 1);
  chunk_prefix_kernel<<<512,256,0,stream>>>(P1);
  chunk_prefix_kernel<<<512,256,0,stream>>>(P2);
  sc_state_kernel<<<gc,256,0,stream>>>(q_bf, s_bf, g, P1, sc);
  window_attn_kernel<<<gc,256,0,stream>>>(q_bf, k_bf, v, sc, o, ps);
  o_state_kernel<<<gc,256,0,stream>>>(ps, g, v, P2, o);
  swish_rms_kernel<<<4096,256,0,stream>>>(o, w_norm, o2);
  gemm_nt<<<g64,256,0,stream>>>(o2, Wo, out, nullptr, 4096,1024,1024);
}

// Round 2
// 1190.433 us; speedup vs baseline: 1.5909x; 1.5909x over previous
//
#include <hip/hip_runtime.h>
#include <stdint.h>

#define B_  2
#define T_  2048
#define D_  1024
#define H_  4
#define S_  64
#define W_  512
#define CK_ 256
#define NC_ 32      // T_/64 chunks
#define BT_ 4096

typedef __attribute__((ext_vector_type(8))) short bf16x8;
typedef __attribute__((ext_vector_type(4))) float f32x4;

__device__ __forceinline__ float bf2f(unsigned short u){ return __uint_as_float(((unsigned int)u)<<16); }
__device__ __forceinline__ unsigned short f2bf(float f){
  unsigned int u = __float_as_uint(f);
  u += 0x7fffu + ((u>>16)&1u);
  return (unsigned short)(u>>16);
}
__device__ __forceinline__ float bflo(unsigned int p){ return __uint_as_float(p<<16); }
__device__ __forceinline__ float bfhi(unsigned int p){ return __uint_as_float(p & 0xffff0000u); }

// ---------------- RMSNorm: x(B*T,D) -> out(B*T,D) fp32 ----------------
__global__ void rmsnorm_kernel(const float* __restrict__ x, const float* __restrict__ w,
                               float* __restrict__ out){
  int row = blockIdx.x, tid = threadIdx.x;
  const float* xr = x + (size_t)row*D_;
  float v0=xr[tid], v1=xr[tid+256], v2=xr[tid+512], v3=xr[tid+768];
  __shared__ float red[256];
  red[tid] = v0*v0+v1*v1+v2*v2+v3*v3;
  __syncthreads();
  for(int s=128;s>0;s>>=1){ if(tid<s) red[tid]+=red[tid+s]; __syncthreads(); }
  float r = rsqrtf(red[0]/(float)D_ + 1e-5f);
  float* orow = out + (size_t)row*D_;
  orow[tid]     = v0*r*w[tid];
  orow[tid+256] = v1*r*w[tid+256];
  orow[tid+512] = v2*r*w[tid+512];
  orow[tid+768] = v3*r*w[tid+768];
}

// ---------------- GEMM-NT: C[M,N] = A[M,K] * Wt[N,K]^T ----------------
// optional fp32 output Cf, optional bf16 output Cbf, optional transposed
// head-aware bf16 output CbfT with layout [b][h][col&255][t] (requires N==1024)
__global__ __launch_bounds__(256) void gemm_nt(const float* __restrict__ A, const float* __restrict__ Wt,
                     float* __restrict__ Cf, unsigned short* __restrict__ Cbf,
                     unsigned short* __restrict__ CbfT,
                     int M, int N, int K){
  __shared__ float As[16][68];
  __shared__ float Bs[16][68];
  int tid = threadIdx.x;
  int tx = tid & 15, ty = tid >> 4;
  int row0 = blockIdx.y*64, col0 = blockIdx.x*64;
  int kq = tid & 15;
  int mq = tid >> 4;
  float acc[4][4] = {};
  for(int kt=0; kt<K; kt+=16){
    #pragma unroll
    for(int r=0;r<4;r++){
      As[kq][mq + r*16] = A [(size_t)(row0 + mq + r*16)*K + kt + kq];
      Bs[kq][mq + r*16] = Wt[(size_t)(col0 + mq + r*16)*K + kt + kq];
    }
    __syncthreads();
    #pragma unroll
    for(int kk=0;kk<16;kk++){
      float a0=As[kk][ty*4+0],a1=As[kk][ty*4+1],a2=As[kk][ty*4+2],a3=As[kk][ty*4+3];
      float b0=Bs[kk][tx*4+0],b1=Bs[kk][tx*4+1],b2=Bs[kk][tx*4+2],b3=Bs[kk][tx*4+3];
      acc[0][0]+=a0*b0; acc[0][1]+=a0*b1; acc[0][2]+=a0*b2; acc[0][3]+=a0*b3;
      acc[1][0]+=a1*b0; acc[1][1]+=a1*b1; acc[1][2]+=a1*b2; acc[1][3]+=a1*b3;
      acc[2][0]+=a2*b0; acc[2][1]+=a2*b1; acc[2][2]+=a2*b2; acc[2][3]+=a2*b3;
      acc[3][0]+=a3*b0; acc[3][1]+=a3*b1; acc[3][2]+=a3*b2; acc[3][3]+=a3*b3;
    }
    __syncthreads();
  }
  int hh = col0 >> 8, bb = row0 >> 11;
  int cv0 = col0 & 255, tl0 = row0 & 2047;
  #pragma unroll
  for(int i=0;i<4;i++){
    #pragma unroll
    for(int j=0;j<4;j++){
      size_t idx = (size_t)(row0+ty*4+i)*N + col0+tx*4+j;
      float val = acc[i][j];
      if(Cf)  Cf[idx]  = val;
      if(Cbf) Cbf[idx] = f2bf(val);
      if(CbfT) CbfT[((size_t)((bb*H_+hh)*256 + cv0+tx*4+j))*T_ + tl0+ty*4+i] = f2bf(val);
    }
  }
}

// ---------------- softmax over 256 (in place), one row per block ----------------
__global__ void softmax256_kernel(float* __restrict__ g){
  int row = blockIdx.x, tid = threadIdx.x;
  float x = g[(size_t)row*256+tid];
  __shared__ float red[256];
  red[tid]=x; __syncthreads();
  for(int s=128;s>0;s>>=1){ if(tid<s) red[tid]=fmaxf(red[tid],red[tid+s]); __syncthreads(); }
  float m = red[0]; __syncthreads();
  float e = expf(x-m);
  red[tid]=e; __syncthreads();
  for(int s=128;s>0;s>>=1){ if(tid<s) red[tid]+=red[tid+s]; __syncthreads(); }
  g[(size_t)row*256+tid] = e/red[0];
}

// ---------------- per-chunk outer product states ----------------
__global__ __launch_bounds__(256) void chunk_outer_kernel(const float* __restrict__ in1f,
    const unsigned short* __restrict__ in1bf,
    const float* __restrict__ g, float* __restrict__ out, int transpose_out){
  int n=blockIdx.x, h=blockIdx.y, b=blockIdx.z;
  int tid=threadIdx.x, t0=n*64;
  __shared__ float g_lds[64][68];
  for(int i=0;i<64;i+=4){
    int rr = i + (tid>>6), cc = tid&63;
    g_lds[rr][cc] = g[((size_t)(b*T_ + t0 + rr))*256 + h*64 + cc];
  }
  __syncthreads();
  float acc[64]={};
  for(int u=0;u<64;u++){
    size_t idx = ((size_t)(b*T_ + t0 + u))*D_ + h*CK_ + tid;
    float a = in1f ? in1f[idx] : bf2f(in1bf[idx]);
    #pragma unroll
    for(int s=0;s<64;s++) acc[s] += a*g_lds[u][s];
  }
  size_t base = (size_t)(b*H_+h)*NC_ + n;
  if(transpose_out){
    #pragma unroll 4
    for(int s=0;s<64;s++) out[(base*64+s)*256 + tid] = acc[s];
  } else {
    #pragma unroll 4
    for(int s=0;s<64;s++) out[(base*256+tid)*64 + s] = acc[s];
  }
}

// ---------------- exclusive prefix over chunks (in place) ----------------
__global__ void chunk_prefix_kernel(float* __restrict__ arr){
  int idx = blockIdx.x*256 + threadIdx.x;
  int bh = idx >> 14, e = idx & 16383;
  float run = 0.f;
  size_t base = (size_t)bh*NC_*16384 + e;
  for(int n=0;n<NC_;n++){
    size_t a = base + (size_t)n*16384;
    float t = arr[a]; arr[a] = run; run += t;
  }
}

// ---------------- sc_state[t,s] = q[t]·S1[:,s] + tril(q·s^T)·g ----------------
__global__ __launch_bounds__(256) void sc_state_kernel(const unsigned short* __restrict__ q_bf,
    const unsigned short* __restrict__ s_bf,
    const float* __restrict__ g, const float* __restrict__ S1, float* __restrict__ sc_state){
  int n=blockIdx.x, h=blockIdx.y, b=blockIdx.z;
  int tid=threadIdx.x, t0=n*64;
  __shared__ unsigned short s_lds[64*260];
  __shared__ float A_lds[64*65];
  for(int i=0;i<64;i++)
    s_lds[i*260+tid] = s_bf[((size_t)(b*T_+t0+i))*D_ + h*CK_ + tid];
  __syncthreads();
  int u = tid & 63;
  #pragma unroll 1
  for(int kk=0;kk<16;kk++){
    int t = (tid>>6) + kk*4;
    const unsigned short* qr = q_bf + ((size_t)(b*T_+t0+t))*D_ + h*CK_;
    float dot=0.f;
    for(int c=0;c<256;c+=2){
      unsigned int qp = *(const unsigned int*)(qr + c);
      unsigned int sp = *(const unsigned int*)(&s_lds[u*260+c]);
      dot += bflo(qp)*bflo(sp) + bfhi(qp)*bfhi(sp);
    }
    A_lds[t*65+u] = (u<=t)? dot : 0.f;
  }
  __syncthreads();
  int s = tid & 63, tb = tid >> 6;
  float acc[16]={};
  size_t s1base = ((size_t)(b*H_+h)*NC_+n)*16384;
  for(int c=0;c<256;c++){
    float st1 = S1[s1base + c*64 + s];
    #pragma unroll
    for(int i=0;i<16;i++){
      float qv = bf2f(q_bf[((size_t)(b*T_+t0+tb*16+i))*D_ + h*CK_ + c]);
      acc[i] += qv*st1;
    }
  }
  for(int uu=0;uu<64;uu++){
    float gv = g[((size_t)(b*T_+t0+uu))*256 + h*64 + s];
    #pragma unroll
    for(int i=0;i<16;i++){
      int t = tb*16+i;
      if(uu<=t) acc[i] += A_lds[t*65+uu]*gv;
    }
  }
  #pragma unroll
  for(int i=0;i<16;i++)
    sc_state[((size_t)(b*H_+h)*T_ + t0+tb*16+i)*64 + s] = acc[i];
}

// ---------------- MFMA fused window attention + joint softmax ----------------
// q strip A-frags in regs; K staged in LDS (stride 260); V^T staged in same
// LDS buffer (stride 72); S f32 round-trip for block softmax; P bf16 A-layout
// round-trip. Wave (sp,np) owns rows 32sp..+31, u/cv half np.
__global__ __launch_bounds__(256,1) void window_attn_mfma(
    const unsigned short* __restrict__ q_bf,
    const unsigned short* __restrict__ k_bf,
    const unsigned short* __restrict__ vt_bf,
    const float* __restrict__ sc_state,
    float* __restrict__ o, float* __restrict__ p_state)
{
  int nt=blockIdx.x, h=blockIdx.y, b=blockIdx.z;
  int tid=threadIdx.x;
  int lane = tid & 63, w = tid >> 6;
  int quad = lane >> 4, lq = lane & 15;
  int sp = w >> 1, np = w & 1;
  int t0 = nt*64, bh = b*H_ + h;
  float slope = exp2f(-2.0f*(float)h);

  __shared__ unsigned short kv_lds[256*72];   // union: K 64x260 (16640) / VT 256x72 (18432)
  __shared__ float S_lds[64*68];
  __shared__ unsigned short P_lds[64*72];
  __shared__ float m_lds[64], l_lds[64], al_lds[64];

  // q A-fragments: A[m=lq][k=quad*8+j], 2 strips x 8 k-steps
  bf16x8 qf[2][8];
  #pragma unroll
  for(int st=0; st<2; st++){
    const unsigned short* qrow = q_bf + ((size_t)(b*T_ + t0 + 32*sp + 16*st + lq))*D_ + h*CK_ + quad*8;
    #pragma unroll
    for(int ks=0; ks<8; ks++)
      qf[st][ks] = *(const bf16x8*)(const void*)(qrow + ks*32);
  }

  // init m,l from state scores; thread (r=tid>>2, part=tid&3)
  int r = tid >> 2, part = tid & 3;
  {
    const float* scrow = sc_state + ((size_t)bh*T_ + t0 + r)*64 + part*16;
    float pm = -1e30f, sv[16];
    #pragma unroll
    for(int i=0;i<16;i++){ sv[i] = scrow[i]; pm = fmaxf(pm, sv[i]); }
    pm = fmaxf(pm, __shfl_xor(pm,1)); pm = fmaxf(pm, __shfl_xor(pm,2));
    float ps = 0.f;
    #pragma unroll
    for(int i=0;i<16;i++) ps += __expf(sv[i]-pm);
    ps += __shfl_xor(ps,1); ps += __shfl_xor(ps,2);
    if(part==0){ m_lds[r]=pm; l_lds[r]=ps; }
  }

  f32x4 o_acc[2][8];
  #pragma unroll
  for(int st=0;st<2;st++)
    #pragma unroll
    for(int nv=0;nv<8;nv++) o_acc[st][nv] = (f32x4){0.f,0.f,0.f,0.f};
  __syncthreads();

  int jt0 = (nt>=8)? nt-8 : 0;
  for(int jt=jt0; jt<=nt; jt++){
    int j0 = jt*64;
    // ---- stage K tile (64 x 256 bf16, LDS stride 260) ----
    {
      int row = tid>>2, seg = tid&3;
      const unsigned short* src = k_bf + ((size_t)(b*T_ + j0 + row))*D_ + h*CK_ + seg*64;
      unsigned short* dst = kv_lds + row*260 + seg*64;
      #pragma unroll
      for(int i=0;i<8;i++) *(bf16x8*)(void*)(dst + i*8) = *(const bf16x8*)(const void*)(src + i*8);
    }
    __syncthreads();
    // ---- QK^T MFMA ----
    f32x4 sacc[2][2];
    #pragma unroll
    for(int st=0;st<2;st++)
      #pragma unroll
      for(int n2=0;n2<2;n2++) sacc[st][n2] = (f32x4){0.f,0.f,0.f,0.f};
    #pragma unroll
    for(int n2=0;n2<2;n2++){
      int n = np*2 + n2;
      #pragma unroll
      for(int ks=0;ks<8;ks++){
        bf16x8 kf = *(const bf16x8*)(const void*)(kv_lds + (n*16+lq)*260 + ks*32 + quad*8);
        sacc[0][n2] = __builtin_amdgcn_mfma_f32_16x16x32_bf16(qf[0][ks], kf, sacc[0][n2], 0,0,0);
        sacc[1][n2] = __builtin_amdgcn_mfma_f32_16x16x32_bf16(qf[1][ks], kf, sacc[1][n2], 0,0,0);
      }
    }
    // bias + mask, write S (f32)
    #pragma unroll
    for(int st=0;st<2;st++){
      #pragma unroll
      for(int n2=0;n2<2;n2++){
        int n = np*2+n2;
        int u = j0 + n*16 + lq;
        #pragma unroll
        for(int i=0;i<4;i++){
          int row = 32*sp + 16*st + quad*4 + i;
          int d = (t0 + row) - u;
          float val = (d>=0 && d<W_) ? sacc[st][n2][i] - slope*(float)d : -1e30f;
          S_lds[row*68 + n*16+lq] = val;
        }
      }
    }
    __syncthreads();
    // ---- block softmax update + P write; stage V^T concurrently ----
    {
      float s16[16], tm = -1e30f;
      #pragma unroll
      for(int i=0;i<16;i++){ s16[i] = S_lds[r*68 + part*16 + i]; tm = fmaxf(tm, s16[i]); }
      tm = fmaxf(tm, __shfl_xor(tm,1)); tm = fmaxf(tm, __shfl_xor(tm,2));
      float m_old = m_lds[r];
      float m_new = fmaxf(m_old, tm);
      float alpha = __expf(m_old - m_new);
      float ts = 0.f;
      union { unsigned short u[16]; bf16x8 v[2]; } pk;
      #pragma unroll
      for(int i=0;i<16;i++){ float p = __expf(s16[i]-m_new); ts += p; pk.u[i] = f2bf(p); }
      ts += __shfl_xor(ts,1); ts += __shfl_xor(ts,2);
      *(bf16x8*)(void*)&P_lds[r*72 + part*16]     = pk.v[0];
      *(bf16x8*)(void*)&P_lds[r*72 + part*16 + 8] = pk.v[1];
      if(part==0){ m_lds[r] = m_new; l_lds[r] = l_lds[r]*alpha + ts; al_lds[r] = alpha; }
      // V^T tile: 256 rows(cv) x 64(u), LDS stride 72
      #pragma unroll
      for(int pass=0; pass<4; pass++){
        int cv = (tid>>2) + 64*pass, useg = (tid&3)*16;
        const unsigned short* src = vt_bf + ((size_t)(bh*256 + cv))*T_ + j0 + useg;
        unsigned short* dst = kv_lds + cv*72 + useg;
        *(bf16x8*)(void*)(dst)   = *(const bf16x8*)(const void*)(src);
        *(bf16x8*)(void*)(dst+8) = *(const bf16x8*)(const void*)(src+8);
      }
    }
    __syncthreads();
    // ---- rescale o_acc, PV MFMA ----
    #pragma unroll
    for(int st=0;st<2;st++){
      #pragma unroll
      for(int i=0;i<4;i++){
        float al = al_lds[32*sp+16*st+quad*4+i];
        #pragma unroll
        for(int nv=0;nv<8;nv++) o_acc[st][nv][i] *= al;
      }
    }
    bf16x8 pa[2][2];
    #pragma unroll
    for(int st=0;st<2;st++)
      #pragma unroll
      for(int k2=0;k2<2;k2++)
        pa[st][k2] = *(const bf16x8*)(const void*)&P_lds[(32*sp+16*st+lq)*72 + k2*32 + quad*8];
    #pragma unroll
    for(int nv=0;nv<8;nv++){
      int cvt = np*8 + nv;
      #pragma unroll
      for(int k2=0;k2<2;k2++){
        bf16x8 vb = *(const bf16x8*)(const void*)(kv_lds + (cvt*16+lq)*72 + k2*32 + quad*8);
        o_acc[0][nv] = __builtin_amdgcn_mfma_f32_16x16x32_bf16(pa[0][k2], vb, o_acc[0][nv], 0,0,0);
        o_acc[1][nv] = __builtin_amdgcn_mfma_f32_16x16x32_bf16(pa[1][k2], vb, o_acc[1][nv], 0,0,0);
      }
    }
    __syncthreads();
  }
  // ---- epilogue: o = o_acc / l ----
  #pragma unroll
  for(int st=0;st<2;st++){
    #pragma unroll
    for(int i=0;i<4;i++){
      int row = 32*sp+16*st+quad*4+i;
      float rl = 1.0f / l_lds[row];
      #pragma unroll
      for(int nv=0;nv<8;nv++){
        int cv = (np*8+nv)*16 + lq;
        o[((size_t)bh*T_ + t0 + row)*256 + cv] = o_acc[st][nv][i] * rl;
      }
    }
  }
  // ---- p_state = exp(sc - m)/l ----
  {
    float mf = m_lds[r], rlf = 1.0f / l_lds[r];
    const float* scrow = sc_state + ((size_t)bh*T_ + t0 + r)*64 + part*16;
    float* pr = p_state + ((size_t)bh*T_ + t0 + r)*64 + part*16;
    #pragma unroll
    for(int i=0;i<16;i++) pr[i] = __expf(scrow[i]-mf)*rlf;
  }
}

// ---------------- o += p_state @ SG + tril(p_state·g^T) @ v ----------------
__global__ __launch_bounds__(256) void o_state_kernel(const float* __restrict__ p_state,
    const float* __restrict__ g,
    const float* __restrict__ v, const float* __restrict__ SG, float* __restrict__ o){
  int n=blockIdx.x, h=blockIdx.y, b=blockIdx.z;
  int tid=threadIdx.x, t0=n*64;
  __shared__ float p_lds[64*69];
  __shared__ float g_lds[64*69];
  __shared__ float M_lds[64*65];
  for(int i=0;i<16;i++){
    int rr = (tid>>6) + i*4, cc = tid&63;
    p_lds[rr*69+cc] = p_state[((size_t)(b*H_+h)*T_ + t0+rr)*64 + cc];
    g_lds[rr*69+cc] = g[((size_t)(b*T_+t0+rr))*256 + h*64 + cc];
  }
  __syncthreads();
  int u = tid & 63;
  #pragma unroll 1
  for(int kk=0;kk<16;kk++){
    int t = (tid>>6) + kk*4;
    float dot=0.f;
    #pragma unroll
    for(int s=0;s<64;s++) dot += p_lds[t*69+s]*g_lds[u*69+s];
    M_lds[t*65+u] = (u<=t)? dot : 0.f;
  }
  __syncthreads();
  float acc[64];
  #pragma unroll
  for(int t=0;t<64;t++) acc[t]=0.f;
  size_t sgbase = ((size_t)(b*H_+h)*NC_+n)*16384;
  for(int s=0;s<64;s++){
    float gsc = SG[sgbase + s*256 + tid];
    #pragma unroll
    for(int t=0;t<64;t++) acc[t] += p_lds[t*69+s]*gsc;
  }
  for(int uu=0;uu<64;uu++){
    float vv = v[((size_t)(b*T_+t0+uu))*D_ + h*CK_ + tid];
    #pragma unroll
    for(int t=0;t<64;t++) acc[t] += M_lds[t*65+uu]*vv;
  }
  #pragma unroll 4
  for(int t=0;t<64;t++){
    size_t oi = ((size_t)(b*H_+h)*T_ + t0+t)*256 + tid;
    o[oi] += acc[t];
  }
}

// ---------------- swish + rmsnorm, gather heads -> (B*T, D) ----------------
__global__ void swish_rms_kernel(const float* __restrict__ o, const float* __restrict__ w,
                                 float* __restrict__ o2){
  int bt=blockIdx.x, tid=threadIdx.x;
  int b = bt >> 11, t = bt & 2047;
  float y[4]; float ss=0.f;
  #pragma unroll
  for(int hh=0;hh<4;hh++){
    float x = o[((size_t)(b*H_+hh)*T_ + t)*256 + tid];
    float yy = x / (1.f + expf(-x));
    y[hh]=yy; ss += yy*yy;
  }
  __shared__ float red[256];
  red[tid]=ss; __syncthreads();
  for(int s2=128;s2>0;s2>>=1){ if(tid<s2) red[tid]+=red[tid+s2]; __syncthreads(); }
  float r = rsqrtf(red[0]/1024.f + 1e-5f);
  #pragma unroll
  for(int hh=0;hh<4;hh++)
    o2[(size_t)bt*1024 + hh*256 + tid] = y[hh]*r*w[hh*256+tid];
}

extern "C" void kernel_launch(void* const* d_in, const int* in_sizes, int n_in,
                              void* d_out, int out_size, void* d_ws, size_t ws_size,
                              hipStream_t stream){
  const float* hidden = (const float*)d_in[0];
  const float* w_norm = (const float*)d_in[1];
  const float* Wq = (const float*)d_in[2];
  const float* Wk = (const float*)d_in[3];
  const float* Wv = (const float*)d_in[4];
  const float* Ws = (const float*)d_in[5];
  const float* Wg = (const float*)d_in[6];
  const float* Wo = (const float*)d_in[7];
  float* out = (float*)d_out;

  char* p = (char*)d_ws;
  auto alloc = [&](size_t bytes)->void*{ void* r = (void*)p; p += (bytes + 255) & ~(size_t)255; return r; };
  float* h   = (float*)alloc(16777216);           // (4096,1024) f32
  float* v   = (float*)alloc(16777216);           // (4096,1024) f32
  float* g   = (float*)alloc(4194304);            // (4096,256)  f32
  float* P1  = (float*)alloc(16777216);           // (8,32,256,64) f32 -> excl prefix; later aliased by vt_bf
  float* P2  = (float*)alloc(16777216);           // (8,32,64,256) f32 -> excl prefix
  float* sc  = (float*)alloc(4194304);            // (8,2048,64)
  float* ps  = (float*)alloc(4194304);            // (8,2048,64)
  float* o   = (float*)alloc(16777216);           // (8,2048,256)
  unsigned short* q_bf = (unsigned short*)alloc(8388608);
  unsigned short* k_bf = (unsigned short*)alloc(8388608);
  unsigned short* s_bf = (unsigned short*)alloc(8388608);
  float* o2 = h;                       // h dead after v-gemm; reuse for post-swish activations
  unsigned short* vt_bf = (unsigned short*)P1;  // P1 dead after sc_state; reuse for V^T bf16 (8MB)

  rmsnorm_kernel<<<4096,256,0,stream>>>(hidden, w_norm, h);
  dim3 g64(16,64), ggrid(4,64);
  gemm_nt<<<g64,256,0,stream>>>(h, Wq, nullptr, q_bf, nullptr, 4096,1024,1024);
  gemm_nt<<<g64,256,0,stream>>>(h, Wk, nullptr, k_bf, nullptr, 4096,1024,1024);
  gemm_nt<<<g64,256,0,stream>>>(h, Ws, nullptr, s_bf, nullptr, 4096,1024,1024);
  gemm_nt<<<ggrid,256,0,stream>>>(h, Wg, g, nullptr, nullptr, 4096,256,1024);
  softmax256_kernel<<<4096,256,0,stream>>>(g);
  dim3 gc(32,4,2);
  chunk_outer_kernel<<<gc,256,0,stream>>>(nullptr, s_bf, g, P1, 0);
  chunk_prefix_kernel<<<512,256,0,stream>>>(P1);
  sc_state_kernel<<<gc,256,0,stream>>>(q_bf, s_bf, g, P1, sc);
  // P1 consumed; now safe to overwrite with vt_bf
  gemm_nt<<<g64,256,0,stream>>>(h, Wv, v, nullptr, vt_bf, 4096,1024,1024);
  chunk_outer_kernel<<<gc,256,0,stream>>>(v, nullptr, g, P2, 1);
  chunk_prefix_kernel<<<512,256,0,stream>>>(P2);
  window_attn_mfma<<<gc,256,0,stream>>>(q_bf, k_bf, vt_bf, sc, o, ps);
  o_state_kernel<<<gc,256,0,stream>>>(ps, g, v, P2, o);
  swish_rms_kernel<<<4096,256,0,stream>>>(o, w_norm, o2);
  gemm_nt<<<g64,256,0,stream>>>(o2, Wo, out, nullptr, nullptr, 4096,1024,1024);
}